// Round 10
// baseline (1340.620 us; speedup 1.0000x reference)
//
#include <hip/hip_runtime.h>
#include <math.h>

constexpr int Bn = 8, Dn = 1024, Tn = 4096, NQn = 32, Kn = 1024, CDn = 8;
constexpr float EPSF = 1e-12f;

// ---- prepass 1: normalized codebooks as half-tables + squared norms -------
__global__ void prep_cbn_kernel(const float* __restrict__ cb,
                                float* __restrict__ cbnA,
                                float* __restrict__ cbnB,
                                float* __restrict__ n2) {
  const int idx = blockIdx.x * 256 + threadIdx.x;  // nq*K + k
  if (idx >= NQn * Kn) return;
  const float* row = cb + (size_t)idx * CDn;
  float v[8];
#pragma unroll
  for (int c = 0; c < 8; ++c) v[c] = row[c];
  float s = 0.f;
#pragma unroll
  for (int c = 0; c < 8; ++c) s += v[c] * v[c];
  const float den = fmaxf(sqrtf(s), EPSF);
  float nv[8];
#pragma unroll
  for (int c = 0; c < 8; ++c) nv[c] = v[c] / den;
  float s2 = 0.f;
#pragma unroll
  for (int c = 0; c < 8; ++c) s2 += nv[c] * nv[c];
#pragma unroll
  for (int c = 0; c < 4; ++c) cbnA[idx * 4 + c] = nv[c];
#pragma unroll
  for (int c = 0; c < 4; ++c) cbnB[idx * 4 + c] = nv[c + 4];
  n2[idx] = s2;
}

// ---- prepass 1b: transpose W_out [nq][d][c] -> [nq][c][d] -----------------
__global__ void prep_wot_kernel(const float* __restrict__ wo,
                                float* __restrict__ wot) {
  const int id = blockIdx.x * 256 + threadIdx.x;  // nq*8192 + d*8 + c
  if (id >= NQn * Dn * CDn) return;
  const int nq = id >> 13;
  const int rem = id & 8191;
  const int d = rem >> 3;
  const int c = rem & 7;
  wot[nq * 8192 + c * 1024 + d] = wo[id];
}

// ---- prepass 2: argmin index for fully-masked positions -------------------
__global__ void prep_midx_kernel(const float* __restrict__ b_in,
                                 const float* __restrict__ cbnA,
                                 const float* __restrict__ cbnB,
                                 const float* __restrict__ n2,
                                 int* __restrict__ midx) {
  const int nq = blockIdx.x;
  const int lane = threadIdx.x;  // 64 threads = 1 wave
  const float* bi = b_in + nq * CDn;
  float ze[8];
#pragma unroll
  for (int c = 0; c < 8; ++c) ze[c] = bi[c];
  float s = 0.f;
#pragma unroll
  for (int c = 0; c < 8; ++c) s += ze[c] * ze[c];
  const float den = fmaxf(sqrtf(s), EPSF);
  float enc[8];
#pragma unroll
  for (int c = 0; c < 8; ++c) enc[c] = ze[c] / den;
  float e2 = 0.f;
#pragma unroll
  for (int c = 0; c < 8; ++c) e2 += enc[c] * enc[c];

  const float* CA = cbnA + (size_t)nq * Kn * 4;
  const float* CB = cbnB + (size_t)nq * Kn * 4;
  const float* NN = n2 + (size_t)nq * Kn;
  float bd = 1e30f;
  int bk = 0;
#pragma unroll 4
  for (int mi = 0; mi < 16; ++mi) {
    const int k = (mi << 6) + lane;
    const float4 c0 = *(const float4*)(CA + (k << 2));
    const float4 c1 = *(const float4*)(CB + (k << 2));
    const float nnk = NN[k];
    float dot = c0.x * enc[0];
    dot = fmaf(c0.y, enc[1], dot);
    dot = fmaf(c0.z, enc[2], dot);
    dot = fmaf(c0.w, enc[3], dot);
    dot = fmaf(c1.x, enc[4], dot);
    dot = fmaf(c1.y, enc[5], dot);
    dot = fmaf(c1.z, enc[6], dot);
    dot = fmaf(c1.w, enc[7], dot);
    const float dd = fmaf(-2.f, dot, e2) + nnk;
    if (dd < bd) { bd = dd; bk = k; }
  }
#pragma unroll
  for (int mask = 1; mask <= 32; mask <<= 1) {
    const float od = __shfl_xor(bd, mask);
    const int ok = __shfl_xor(bk, mask);
    const bool take = (od < bd) || (od == bd && ok < bk);
    bd = take ? od : bd;
    bk = take ? ok : bk;
  }
  if (lane == 0) midx[nq] = bk;
}

// ---- masked-region fill: qout=0, idx=midx for t >= ceil(len/4)*4 ----------
__global__ void fill_masked_kernel(const int* __restrict__ lenp,
                                   const int* __restrict__ midx,
                                   float* __restrict__ out) {
  const int blk = blockIdx.x;  // 8 b x 64 chunks of 64 t
  const int b = blk >> 6;
  const int tstart = (blk & 63) << 6;
  const int tid = threadIdx.x;
  float* qout = out;
  float* idxout = out + (size_t)Bn * Dn * Tn;
  float* lenout = idxout + (size_t)NQn * Bn * Tn;
  const int len = lenp[b];
  if (blk == 0 && tid < 8) lenout[tid] = (float)lenp[tid];
  const int ag4 = ((len + 3) >> 2) << 2;  // first masked t (4-aligned)
  if (tstart + 63 < ag4) return;          // chunk fully active
  const size_t zb = (size_t)b * Dn * Tn;
  float4 zv; zv.x = 0.f; zv.y = 0.f; zv.z = 0.f; zv.w = 0.f;
  // qout zeros: 1024 d x 16 quads
#pragma unroll 4
  for (int it = 0; it < 64; ++it) {
    const int idx = (it << 8) + tid;
    const int d = idx >> 4;
    const int t = tstart + ((idx & 15) << 2);
    if (t >= ag4) *(float4*)(qout + zb + (size_t)d * Tn + t) = zv;
  }
  // idx fills: 32 nq x 16 quads
#pragma unroll
  for (int it = 0; it < 2; ++it) {
    const int idx = (it << 8) + tid;
    const int nq = idx >> 4;
    const int t = tstart + ((idx & 15) << 2);
    if (t >= ag4) {
      const float v = (float)midx[nq];
      float4 iv; iv.x = v; iv.y = v; iv.z = v; iv.w = v;
      *(float4*)(idxout + (size_t)(nq * Bn + b) * Tn + t) = iv;
    }
  }
}

// ---- async global->LDS DMA, 16 B per lane ---------------------------------
__device__ __forceinline__ void dma_lds16(const float* g, float* l) {
  __builtin_amdgcn_global_load_lds(
      (const __attribute__((address_space(1))) void*)g,
      (__attribute__((address_space(3))) void*)l, 16, 0, 0);
}

// ---------------- main kernel ---------------------------------------------
// R8/R9 (820/829 us, VALUBusy ~61%) proved all table streams are handled;
// the remaining ~39% stall is the serial reduce/argmin chain suffered in
// LOCKSTEP: barriers align all 8 waves, so both waves of each SIMD stall
// together. Occupancy is VGPR-granularity-pinned at 2 waves/SIMD.
// R10: phase-staggered wave groups. A = waves 0-3, B = waves 4-7 (with
// round-robin wave->SIMD mapping each SIMD hosts one A + one B). 65 slots
// of half-iterations: per slot, A runs phase1(n) (in_proj+reduce+argmin:
// serial-heavy) while B runs phase2(n-1) (gather+out_proj: FMA-dense) ->
// when the A-wave stalls in shfl chains the B-wave issues FMAs.
// Staging (poison-free per R8's vmcnt model): even-slot top issues
// Wi(n+1)+NN(n+1) (36 KB), odd-slot top issues WT(n+1) (32 KB); each
// drains free at the slot-end vmcnt(0). CA/CB move back to global
// (consumed ~3k cy after slot top -> free drain; R9 showed these streams
// are interchangeable with LDS). Only bkv[4] lives across a barrier
// (R9-proven no-spill). LDS: sWi[2] 64K + sWT[2] 64K + sNN[2] 8K + sBI 1K
// = 140288 B. Arithmetic op-identical to rounds 0-9 -> bit-identical
// output. Spill tripwire: WRITE_SIZE ~80 MB.
__global__ __launch_bounds__(512, 2) void rvq_main_kernel(
    const float* __restrict__ z, const int* __restrict__ lenp,
    const float* __restrict__ W_in, const float* __restrict__ b_in,
    const float* __restrict__ wotg, const float* __restrict__ b_out,
    const float* __restrict__ cbraw, const float* __restrict__ cbnAg,
    const float* __restrict__ cbnBg, const float* __restrict__ n2g,
    float* __restrict__ out) {
  __shared__ __align__(16) float sWi[2][8192];  // 64 KB dbuf (in_proj W)
  __shared__ __align__(16) float sWT[2][8192];  // 64 KB dbuf (out_proj W^T)
  __shared__ __align__(16) float sNN[2][1024];  //  8 KB dbuf (cbn |.|^2)
  __shared__ __align__(16) float sBI[256];      //  1 KB static (b_in)

  const int tid = threadIdx.x;
  const int lane = tid & 63;
  const int w = tid >> 6;

  // ---- active-group packing ----------------------------------------------
  int pre[9];
  pre[0] = 0;
#pragma unroll
  for (int bb = 0; bb < 8; ++bb) pre[bb + 1] = pre[bb] + ((lenp[bb] + 3) >> 2);
  const int total = pre[8];
  const int g = blockIdx.x * 8 + w;
  if (blockIdx.x * 8 >= total) return;  // whole block idle (before barriers)
  const bool active = (g < total);      // wave-uniform

  int b = 0, tg = 0, len = 0;
  if (active) {
    while (g >= pre[b + 1]) ++b;
    tg = g - pre[b];
    len = lenp[b];
  }
  const int tcol = tg << 2;
  const size_t zb = (size_t)b * Dn * Tn;

  float* qout = out;
  float* idxout = out + (size_t)Bn * Dn * Tn;

  float m[4];
#pragma unroll
  for (int cc = 0; cc < 4; ++cc) m[cc] = (tcol + cc < len) ? 1.0f : 0.0f;

  // ---- init residual = z * mask ------------------------------------------
  float r[4][16];
  if (active) {
#pragma unroll
    for (int j = 0; j < 4; ++j) {
#pragma unroll
      for (int i = 0; i < 4; ++i) {
        const int d = (j << 8) + (lane << 2) + i;
        const float4 a0 = *(const float4*)(z + zb + (size_t)d * Tn + tcol);
        const int q = (j << 2) + i;
        r[0][q] = a0.x * m[0]; r[1][q] = a0.y * m[1];
        r[2][q] = a0.z * m[2]; r[3][q] = a0.w * m[3];
      }
    }
  }

  const int b0 = lane & 1, b1 = (lane >> 1) & 1, b2 = (lane >> 2) & 1;

  // ---- prologue: stage Wi(0)/WT(0) (all waves) + NN(0)/BI (wave 0) -------
  {
    const float* baseW = W_in + (w << 10);
    float* dW = &sWi[0][w << 10];
#pragma unroll
    for (int q = 0; q < 4; ++q)
      dma_lds16(baseW + (q << 8) + (lane << 2), dW + (q << 8));
    const float* baseT = wotg + (w << 10);
    float* dT = &sWT[0][w << 10];
#pragma unroll
    for (int q = 0; q < 4; ++q)
      dma_lds16(baseT + (q << 8) + (lane << 2), dT + (q << 8));
    if (w == 0) {
#pragma unroll
      for (int q = 0; q < 4; ++q)
        dma_lds16(n2g + (q << 8) + (lane << 2), &sNN[0][q << 8]);
      dma_lds16(b_in + (lane << 2), sBI);
    }
  }
  asm volatile("s_waitcnt vmcnt(0)" ::: "memory");
  __syncthreads();

  const int shift = (w < 4) ? 0 : 1;  // group A leads, B lags one slot
  int bkv[4] = {0, 0, 0, 0};          // carried from phase1 to phase2

#pragma unroll 1
  for (int s = 0; s < 2 * NQn + 1; ++s) {
    // ---- slot-top staging (all waves; <=36 KB/slot, drains free) ---------
    const int ns = s >> 1;
    if (!(s & 1)) {
      if (ns + 1 < NQn) {
        const float* baseW = W_in + (size_t)(ns + 1) * 8192 + (w << 10);
        float* dW = &sWi[(ns + 1) & 1][w << 10];
#pragma unroll
        for (int q = 0; q < 4; ++q)
          dma_lds16(baseW + (q << 8) + (lane << 2), dW + (q << 8));
        if (w == 0) {
          const float* baseN = n2g + (size_t)(ns + 1) * 1024;
#pragma unroll
          for (int q = 0; q < 4; ++q)
            dma_lds16(baseN + (q << 8) + (lane << 2), &sNN[(ns + 1) & 1][q << 8]);
        }
      }
    } else {
      if (ns + 1 < NQn) {
        const float* baseT = wotg + (size_t)(ns + 1) * 8192 + (w << 10);
        float* dT = &sWT[(ns + 1) & 1][w << 10];
#pragma unroll
        for (int q = 0; q < 4; ++q)
          dma_lds16(baseT + (q << 8) + (lane << 2), dT + (q << 8));
      }
    }

    const int t = s - shift;  // wave-local half-phase counter
    if (t >= 0 && t < 2 * NQn && active) {
      const int n = t >> 1;
      if (!(t & 1)) {
        // ================= PHASE 1: in_proj + reduce + argmin =============
        const float* Wi = &sWi[n & 1][0];

        float part[4][8];
#pragma unroll
        for (int cc = 0; cc < 4; ++cc)
#pragma unroll
          for (int c = 0; c < 8; ++c) part[cc][c] = 0.f;
#pragma unroll
        for (int c = 0; c < 8; ++c) {
#pragma unroll
          for (int j = 0; j < 4; ++j) {
            const float4 wv = *(const float4*)(Wi + (c << 10) + (j << 8) + (lane << 2));
#pragma unroll
            for (int cc = 0; cc < 4; ++cc) {
              part[cc][c] = fmaf(wv.x, r[cc][(j << 2) + 0], part[cc][c]);
              part[cc][c] = fmaf(wv.y, r[cc][(j << 2) + 1], part[cc][c]);
              part[cc][c] = fmaf(wv.z, r[cc][(j << 2) + 2], part[cc][c]);
              part[cc][c] = fmaf(wv.w, r[cc][(j << 2) + 3], part[cc][c]);
            }
          }
        }
        const float biv = sBI[(n << 3) + (lane & 7)];

        float ef[4][8], e2v[4];
#pragma unroll
        for (int cc = 0; cc < 4; ++cc) {
          float u0, u1, u2, u3, v0, v1, t2;
          {
            float k0 = b0 ? part[cc][1] : part[cc][0];
            float s0 = b0 ? part[cc][0] : part[cc][1];
            u0 = k0 + __shfl_xor(s0, 1);
            float k1 = b0 ? part[cc][3] : part[cc][2];
            float s1 = b0 ? part[cc][2] : part[cc][3];
            u1 = k1 + __shfl_xor(s1, 1);
            float k2 = b0 ? part[cc][5] : part[cc][4];
            float s2 = b0 ? part[cc][4] : part[cc][5];
            u2 = k2 + __shfl_xor(s2, 1);
            float k3 = b0 ? part[cc][7] : part[cc][6];
            float s3 = b0 ? part[cc][6] : part[cc][7];
            u3 = k3 + __shfl_xor(s3, 1);
          }
          v0 = (b1 ? u1 : u0) + __shfl_xor(b1 ? u0 : u1, 2);
          v1 = (b1 ? u3 : u2) + __shfl_xor(b1 ? u2 : u3, 2);
          t2 = (b2 ? v1 : v0) + __shfl_xor(b2 ? v0 : v1, 4);
          t2 += __shfl_xor(t2, 8);
          t2 += __shfl_xor(t2, 16);
          t2 += __shfl_xor(t2, 32);
          const float zec = t2 + biv;  // lane holds z_e[c = lane&7]
          float nn = zec * zec;
          nn += __shfl_xor(nn, 1);
          nn += __shfl_xor(nn, 2);
          nn += __shfl_xor(nn, 4);
          const float den = fmaxf(sqrtf(nn), EPSF);
          const float ec = zec / den;
          float e2 = ec * ec;
          e2 += __shfl_xor(e2, 1);
          e2 += __shfl_xor(e2, 2);
          e2 += __shfl_xor(e2, 4);
          e2v[cc] = e2;
#pragma unroll
          for (int c = 0; c < 8; ++c) ef[cc][c] = __shfl(ec, c);
        }

        // argmin: CA/CB global (L2, consumed ~3k cy after slot top), NN LDS
        const float* CA = cbnAg + (size_t)n * Kn * 4;
        const float* CB = cbnBg + (size_t)n * Kn * 4;
        const float* NN = &sNN[n & 1][0];
        float bdv[4];
#pragma unroll
        for (int cc = 0; cc < 4; ++cc) { bdv[cc] = 1e30f; bkv[cc] = 0; }
#pragma unroll 4
        for (int mi = 0; mi < 16; ++mi) {
          const int k = (mi << 6) + lane;
          const float4 c0 = *(const float4*)(CA + (k << 2));
          const float4 c1 = *(const float4*)(CB + (k << 2));
          const float nnk = NN[k];
#pragma unroll
          for (int cc = 0; cc < 4; ++cc) {
            float dot = c0.x * ef[cc][0];
            dot = fmaf(c0.y, ef[cc][1], dot);
            dot = fmaf(c0.z, ef[cc][2], dot);
            dot = fmaf(c0.w, ef[cc][3], dot);
            dot = fmaf(c1.x, ef[cc][4], dot);
            dot = fmaf(c1.y, ef[cc][5], dot);
            dot = fmaf(c1.z, ef[cc][6], dot);
            dot = fmaf(c1.w, ef[cc][7], dot);
            const float dd = fmaf(-2.f, dot, e2v[cc]) + nnk;
            if (dd < bdv[cc]) { bdv[cc] = dd; bkv[cc] = k; }  // first-min in k
          }
        }
#pragma unroll
        for (int mask = 1; mask <= 32; mask <<= 1) {
#pragma unroll
          for (int cc = 0; cc < 4; ++cc) {
            const float od = __shfl_xor(bdv[cc], mask);
            const int ok = __shfl_xor(bkv[cc], mask);
            const bool take = (od < bdv[cc]) || (od == bdv[cc] && ok < bkv[cc]);
            bdv[cc] = take ? od : bdv[cc];
            bkv[cc] = take ? ok : bkv[cc];
          }
        }
      } else {
        // ================= PHASE 2: gather + out_proj =====================
        const float* CBR = cbraw + (size_t)n * 8192;
        float zq[4][8];
#pragma unroll
        for (int cc = 0; cc < 4; ++cc) {
          const float4 q0 = *(const float4*)(CBR + (bkv[cc] << 3));
          const float4 q1 = *(const float4*)(CBR + (bkv[cc] << 3) + 4);
          zq[cc][0] = q0.x; zq[cc][1] = q0.y; zq[cc][2] = q0.z; zq[cc][3] = q0.w;
          zq[cc][4] = q1.x; zq[cc][5] = q1.y; zq[cc][6] = q1.z; zq[cc][7] = q1.w;
        }
        if (lane == 0) {
          float4 iv;
          iv.x = (float)bkv[0]; iv.y = (float)bkv[1];
          iv.z = (float)bkv[2]; iv.w = (float)bkv[3];
          *(float4*)(idxout + (size_t)(n * Bn + b) * Tn + tcol) = iv;
        }

        const float* WT = &sWT[n & 1][0];
        const float* BO = b_out + (size_t)n * 1024;  // global, L1/L2-hot
#pragma unroll
        for (int j = 0; j < 4; ++j) {
          const float4 bov = *(const float4*)(BO + (j << 8) + (lane << 2));
          float acc[4][4];
#pragma unroll
          for (int i = 0; i < 4; ++i)
#pragma unroll
            for (int cc = 0; cc < 4; ++cc) acc[i][cc] = 0.f;
#pragma unroll
          for (int c = 0; c < 8; ++c) {
            const float4 wv = *(const float4*)(WT + (c << 10) + (j << 8) + (lane << 2));
#pragma unroll
            for (int cc = 0; cc < 4; ++cc) {
              acc[0][cc] = fmaf(wv.x, zq[cc][c], acc[0][cc]);
              acc[1][cc] = fmaf(wv.y, zq[cc][c], acc[1][cc]);
              acc[2][cc] = fmaf(wv.z, zq[cc][c], acc[2][cc]);
              acc[3][cc] = fmaf(wv.w, zq[cc][c], acc[3][cc]);
            }
          }
#pragma unroll
          for (int i = 0; i < 4; ++i) {
            const float bod = (i == 0) ? bov.x : (i == 1) ? bov.y : (i == 2) ? bov.z : bov.w;
#pragma unroll
            for (int cc = 0; cc < 4; ++cc) {
              const float zo = acc[i][cc] + bod;
              r[cc][(j << 2) + i] = fmaf(-m[cc], zo, r[cc][(j << 2) + i]);
            }
          }
        }
      }  // phase select
    }  // t in range && active

    // ---- slot end: own DMAs drained (issued at top, slot >> 2k cy) -------
    asm volatile("s_waitcnt vmcnt(0)" ::: "memory");
    __syncthreads();
  }  // s

  if (!active) return;

  // ---- final: qout = (z - residual) * mask --------------------------------
#pragma unroll
  for (int j = 0; j < 4; ++j) {
#pragma unroll
    for (int i = 0; i < 4; ++i) {
      const int d = (j << 8) + (lane << 2) + i;
      const float4 a0 = *(const float4*)(z + zb + (size_t)d * Tn + tcol);
      const int q = (j << 2) + i;
      float4 o0;
      o0.x = (a0.x - r[0][q]) * m[0];
      o0.y = (a0.y - r[1][q]) * m[1];
      o0.z = (a0.z - r[2][q]) * m[2];
      o0.w = (a0.w - r[3][q]) * m[3];
      *(float4*)(qout + zb + (size_t)d * Tn + tcol) = o0;
    }
  }
}

extern "C" void kernel_launch(void* const* d_in, const int* in_sizes, int n_in,
                              void* d_out, int out_size, void* d_ws, size_t ws_size,
                              hipStream_t stream) {
  const float* z = (const float*)d_in[0];
  const int* input_length = (const int*)d_in[1];
  const float* W_in = (const float*)d_in[2];
  const float* b_in = (const float*)d_in[3];
  const float* W_out = (const float*)d_in[4];
  const float* b_out = (const float*)d_in[5];
  const float* codebooks = (const float*)d_in[6];
  float* out = (float*)d_out;

  float* wsf = (float*)d_ws;
  float* cbnA = wsf;                          // 32*1024*4 floats
  float* cbnB = cbnA + (size_t)NQn * Kn * 4;  // 32*1024*4
  float* n2 = cbnB + (size_t)NQn * Kn * 4;    // 32*1024
  float* wot = n2 + (size_t)NQn * Kn;         // 32*8192
  int* midx = (int*)(wot + (size_t)NQn * CDn * Dn);

  prep_cbn_kernel<<<(NQn * Kn + 255) / 256, 256, 0, stream>>>(codebooks, cbnA, cbnB, n2);
  prep_wot_kernel<<<(NQn * Dn * CDn + 255) / 256, 256, 0, stream>>>(W_out, wot);
  prep_midx_kernel<<<NQn, 64, 0, stream>>>(b_in, cbnA, cbnB, n2, midx);
  fill_masked_kernel<<<8 * 64, 256, 0, stream>>>(input_length, midx, out);
  rvq_main_kernel<<<(Bn * Tn / 4) / 8, 512, 0, stream>>>(
      z, input_length, W_in, b_in, wot, b_out, codebooks, cbnA, cbnB, n2, out);
}

// Round 11
// 1027.734 us; speedup vs baseline: 1.3044x; 1.3044x over previous
//
#include <hip/hip_runtime.h>
#include <math.h>

constexpr int Bn = 8, Dn = 1024, Tn = 4096, NQn = 32, Kn = 1024, CDn = 8;
constexpr float EPSF = 1e-12f;

// ---- prepass 1: normalized codebooks as half-tables + squared norms -------
__global__ void prep_cbn_kernel(const float* __restrict__ cb,
                                float* __restrict__ cbnA,
                                float* __restrict__ cbnB,
                                float* __restrict__ n2) {
  const int idx = blockIdx.x * 256 + threadIdx.x;  // nq*K + k
  if (idx >= NQn * Kn) return;
  const float* row = cb + (size_t)idx * CDn;
  float v[8];
#pragma unroll
  for (int c = 0; c < 8; ++c) v[c] = row[c];
  float s = 0.f;
#pragma unroll
  for (int c = 0; c < 8; ++c) s += v[c] * v[c];
  const float den = fmaxf(sqrtf(s), EPSF);
  float nv[8];
#pragma unroll
  for (int c = 0; c < 8; ++c) nv[c] = v[c] / den;
  float s2 = 0.f;
#pragma unroll
  for (int c = 0; c < 8; ++c) s2 += nv[c] * nv[c];
#pragma unroll
  for (int c = 0; c < 4; ++c) cbnA[idx * 4 + c] = nv[c];
#pragma unroll
  for (int c = 0; c < 4; ++c) cbnB[idx * 4 + c] = nv[c + 4];
  n2[idx] = s2;
}

// ---- prepass 1b: transpose W_out [nq][d][c] -> [nq][c][d] -----------------
__global__ void prep_wot_kernel(const float* __restrict__ wo,
                                float* __restrict__ wot) {
  const int id = blockIdx.x * 256 + threadIdx.x;  // nq*8192 + d*8 + c
  if (id >= NQn * Dn * CDn) return;
  const int nq = id >> 13;
  const int rem = id & 8191;
  const int d = rem >> 3;
  const int c = rem & 7;
  wot[nq * 8192 + c * 1024 + d] = wo[id];
}

// ---- prepass 2: argmin index for fully-masked positions -------------------
__global__ void prep_midx_kernel(const float* __restrict__ b_in,
                                 const float* __restrict__ cbnA,
                                 const float* __restrict__ cbnB,
                                 const float* __restrict__ n2,
                                 int* __restrict__ midx) {
  const int nq = blockIdx.x;
  const int lane = threadIdx.x;  // 64 threads = 1 wave
  const float* bi = b_in + nq * CDn;
  float ze[8];
#pragma unroll
  for (int c = 0; c < 8; ++c) ze[c] = bi[c];
  float s = 0.f;
#pragma unroll
  for (int c = 0; c < 8; ++c) s += ze[c] * ze[c];
  const float den = fmaxf(sqrtf(s), EPSF);
  float enc[8];
#pragma unroll
  for (int c = 0; c < 8; ++c) enc[c] = ze[c] / den;
  float e2 = 0.f;
#pragma unroll
  for (int c = 0; c < 8; ++c) e2 += enc[c] * enc[c];

  const float* CA = cbnA + (size_t)nq * Kn * 4;
  const float* CB = cbnB + (size_t)nq * Kn * 4;
  const float* NN = n2 + (size_t)nq * Kn;
  float bd = 1e30f;
  int bk = 0;
#pragma unroll 4
  for (int mi = 0; mi < 16; ++mi) {
    const int k = (mi << 6) + lane;
    const float4 c0 = *(const float4*)(CA + (k << 2));
    const float4 c1 = *(const float4*)(CB + (k << 2));
    const float nnk = NN[k];
    float dot = c0.x * enc[0];
    dot = fmaf(c0.y, enc[1], dot);
    dot = fmaf(c0.z, enc[2], dot);
    dot = fmaf(c0.w, enc[3], dot);
    dot = fmaf(c1.x, enc[4], dot);
    dot = fmaf(c1.y, enc[5], dot);
    dot = fmaf(c1.z, enc[6], dot);
    dot = fmaf(c1.w, enc[7], dot);
    const float dd = fmaf(-2.f, dot, e2) + nnk;
    if (dd < bd) { bd = dd; bk = k; }
  }
#pragma unroll
  for (int mask = 1; mask <= 32; mask <<= 1) {
    const float od = __shfl_xor(bd, mask);
    const int ok = __shfl_xor(bk, mask);
    const bool take = (od < bd) || (od == bd && ok < bk);
    bd = take ? od : bd;
    bk = take ? ok : bk;
  }
  if (lane == 0) midx[nq] = bk;
}

// ---- masked-region fill: qout=0, idx=midx for t >= ceil(len/4)*4 ----------
__global__ void fill_masked_kernel(const int* __restrict__ lenp,
                                   const int* __restrict__ midx,
                                   float* __restrict__ out) {
  const int blk = blockIdx.x;  // 8 b x 64 chunks of 64 t
  const int b = blk >> 6;
  const int tstart = (blk & 63) << 6;
  const int tid = threadIdx.x;
  float* qout = out;
  float* idxout = out + (size_t)Bn * Dn * Tn;
  float* lenout = idxout + (size_t)NQn * Bn * Tn;
  const int len = lenp[b];
  if (blk == 0 && tid < 8) lenout[tid] = (float)lenp[tid];
  const int ag4 = ((len + 3) >> 2) << 2;  // first masked t (4-aligned)
  if (tstart + 63 < ag4) return;          // chunk fully active
  const size_t zb = (size_t)b * Dn * Tn;
  float4 zv; zv.x = 0.f; zv.y = 0.f; zv.z = 0.f; zv.w = 0.f;
  // qout zeros: 1024 d x 16 quads
#pragma unroll 4
  for (int it = 0; it < 64; ++it) {
    const int idx = (it << 8) + tid;
    const int d = idx >> 4;
    const int t = tstart + ((idx & 15) << 2);
    if (t >= ag4) *(float4*)(qout + zb + (size_t)d * Tn + t) = zv;
  }
  // idx fills: 32 nq x 16 quads
#pragma unroll
  for (int it = 0; it < 2; ++it) {
    const int idx = (it << 8) + tid;
    const int nq = idx >> 4;
    const int t = tstart + ((idx & 15) << 2);
    if (t >= ag4) {
      const float v = (float)midx[nq];
      float4 iv; iv.x = v; iv.y = v; iv.z = v; iv.w = v;
      *(float4*)(idxout + (size_t)(nq * Bn + b) * Tn + t) = iv;
    }
  }
}

// ---- async global->LDS DMA, 16 B per lane ---------------------------------
// LDS dest is wave-uniform base; HW adds lane*16. Global src is per-lane.
__device__ __forceinline__ void dma_lds16(const float* g, float* l) {
  __builtin_amdgcn_global_load_lds(
      (const __attribute__((address_space(1))) void*)g,
      (__attribute__((address_space(3))) void*)l, 16, 0, 0);
}

// ---------------- main kernel ---------------------------------------------
// R8 (820 us, VALUBusy 62%) is the proven base: poison-free LDS staging,
// one vmcnt(0)+barrier per nq. Its remaining ~38% stall is ISSUE-COLLISION
// + correlated dependency stalls: the per-nq barrier keeps both waves of a
// SIMD at the same instruction, so they stall together (shfl chains) and
// fight for the VALU port otherwise. R10's stagger fixed correlation but
// paid 2x barriers + max-phase per slot -> regressed.
// R11: de-correlate WITHOUT extra barriers -- split into TWO independent
// 256-thread (4-wave) blocks per CU. Barriers are block-local, so the two
// co-resident blocks drift to uncorrelated phases; each SIMD hosts one wave
// of each block (round-robin wave->SIMD) -> when one stalls, the other
// issues. Fit: LDS/block = sWi[2] 64K + sNN[2] 8K + sBI 1K = 73728 B;
// 2 blocks = 147456 <= 163840. VGPR: 2 x 4 waves x 128 = 1024 = CU pool
// (the empirical 8-waves-at-128-VGPR pin), so both blocks co-reside.
// CA/CB go back to per-wave global (fits R8's poison-free rule: argmin's
// loads issue ~5k cy after the slot-top DMAs -> drains free; 16-deep ILP
// covers L2 latency; chip L2 demand ~24 TB/s < 34.5 ceiling). WT/BO were
// already global in R8. Arithmetic op-identical -> bit-identical output.
// Spill tripwire: WRITE_SIZE ~80 MB; (256,2) -> 128-VGPR budget (R4-cal.).
__global__ __launch_bounds__(256, 2) void rvq_main_kernel(
    const float* __restrict__ z, const int* __restrict__ lenp,
    const float* __restrict__ W_in, const float* __restrict__ b_in,
    const float* __restrict__ wotg, const float* __restrict__ b_out,
    const float* __restrict__ cbraw, const float* __restrict__ cbnAg,
    const float* __restrict__ cbnBg, const float* __restrict__ n2g,
    float* __restrict__ out) {
  __shared__ __align__(16) float sWi[2][8192];  // 64 KB dbuf (in_proj W)
  __shared__ __align__(16) float sNN[2][1024];  //  8 KB dbuf (cbn |.|^2)
  __shared__ __align__(16) float sBI[256];      //  1 KB static (b_in)

  const int tid = threadIdx.x;
  const int lane = tid & 63;
  const int w = tid >> 6;  // 0..3

  // ---- active-group packing ----------------------------------------------
  int pre[9];
  pre[0] = 0;
#pragma unroll
  for (int bb = 0; bb < 8; ++bb) pre[bb + 1] = pre[bb] + ((lenp[bb] + 3) >> 2);
  const int total = pre[8];
  const int g = blockIdx.x * 4 + w;
  if (blockIdx.x * 4 >= total) return;  // whole block idle (before barriers)
  const bool active = (g < total);      // wave-uniform

  int b = 0, tg = 0, len = 0;
  if (active) {
    while (g >= pre[b + 1]) ++b;
    tg = g - pre[b];
    len = lenp[b];
  }
  const int tcol = tg << 2;
  const size_t zb = (size_t)b * Dn * Tn;

  float* qout = out;
  float* idxout = out + (size_t)Bn * Dn * Tn;

  float m[4];
#pragma unroll
  for (int cc = 0; cc < 4; ++cc) m[cc] = (tcol + cc < len) ? 1.0f : 0.0f;

  // ---- init residual = z * mask ------------------------------------------
  float r[4][16];
  if (active) {
#pragma unroll
    for (int j = 0; j < 4; ++j) {
#pragma unroll
      for (int i = 0; i < 4; ++i) {
        const int d = (j << 8) + (lane << 2) + i;
        const float4 a0 = *(const float4*)(z + zb + (size_t)d * Tn + tcol);
        const int q = (j << 2) + i;
        r[0][q] = a0.x * m[0]; r[1][q] = a0.y * m[1];
        r[2][q] = a0.z * m[2]; r[3][q] = a0.w * m[3];
      }
    }
  }

  const int b0 = lane & 1, b1 = (lane >> 1) & 1, b2 = (lane >> 2) & 1;

  // ---- prologue: stage Wi(0) (4 waves x 2048 floats) + NN(0)/BI (w0) -----
  {
    const float* base = W_in + (w << 11);
    float* ldst = &sWi[0][w << 11];
#pragma unroll
    for (int q = 0; q < 8; ++q)
      dma_lds16(base + (q << 8) + (lane << 2), ldst + (q << 8));
    if (w == 0) {
#pragma unroll
      for (int q = 0; q < 4; ++q)
        dma_lds16(n2g + (q << 8) + (lane << 2), &sNN[0][q << 8]);
      dma_lds16(b_in + (lane << 2), sBI);
    }
  }
  asm volatile("s_waitcnt vmcnt(0)" ::: "memory");
  __syncthreads();

  int cur = 0;
#pragma unroll 1
  for (int nq = 0; nq < NQn; ++nq) {
    // ---- async prefetch Wi/NN(nq+1) into the other buffer ----------------
    if (nq + 1 < NQn) {
      const float* base = W_in + (size_t)(nq + 1) * 8192 + (w << 11);
      float* ldst = &sWi[cur ^ 1][w << 11];
#pragma unroll
      for (int q = 0; q < 8; ++q)
        dma_lds16(base + (q << 8) + (lane << 2), ldst + (q << 8));
      if (w == 0) {
        const float* baseN = n2g + (size_t)(nq + 1) * 1024;
#pragma unroll
        for (int q = 0; q < 4; ++q)
          dma_lds16(baseN + (q << 8) + (lane << 2), &sNN[cur ^ 1][q << 8]);
      }
    }

    if (active) {
      const float* Wi = &sWi[cur][0];
      const float* NN = &sNN[cur][0];

      // ---- in_proj (LDS): per-lane partials over 16 d's, 8 channels ------
      float part[4][8];
#pragma unroll
      for (int cc = 0; cc < 4; ++cc)
#pragma unroll
        for (int c = 0; c < 8; ++c) part[cc][c] = 0.f;
#pragma unroll
      for (int c = 0; c < 8; ++c) {
#pragma unroll
        for (int j = 0; j < 4; ++j) {
          const float4 wv = *(const float4*)(Wi + (c << 10) + (j << 8) + (lane << 2));
#pragma unroll
          for (int cc = 0; cc < 4; ++cc) {
            part[cc][c] = fmaf(wv.x, r[cc][(j << 2) + 0], part[cc][c]);
            part[cc][c] = fmaf(wv.y, r[cc][(j << 2) + 1], part[cc][c]);
            part[cc][c] = fmaf(wv.z, r[cc][(j << 2) + 2], part[cc][c]);
            part[cc][c] = fmaf(wv.w, r[cc][(j << 2) + 3], part[cc][c]);
          }
        }
      }
      const float biv = sBI[(nq << 3) + (lane & 7)];

      // ---- transpose-reduce 8 partials across 64 lanes; normalize --------
      float ef[4][8], e2v[4];
#pragma unroll
      for (int cc = 0; cc < 4; ++cc) {
        float u0, u1, u2, u3, v0, v1, t;
        {
          float k0 = b0 ? part[cc][1] : part[cc][0];
          float s0 = b0 ? part[cc][0] : part[cc][1];
          u0 = k0 + __shfl_xor(s0, 1);
          float k1 = b0 ? part[cc][3] : part[cc][2];
          float s1 = b0 ? part[cc][2] : part[cc][3];
          u1 = k1 + __shfl_xor(s1, 1);
          float k2 = b0 ? part[cc][5] : part[cc][4];
          float s2 = b0 ? part[cc][4] : part[cc][5];
          u2 = k2 + __shfl_xor(s2, 1);
          float k3 = b0 ? part[cc][7] : part[cc][6];
          float s3 = b0 ? part[cc][6] : part[cc][7];
          u3 = k3 + __shfl_xor(s3, 1);
        }
        v0 = (b1 ? u1 : u0) + __shfl_xor(b1 ? u0 : u1, 2);
        v1 = (b1 ? u3 : u2) + __shfl_xor(b1 ? u2 : u3, 2);
        t = (b2 ? v1 : v0) + __shfl_xor(b2 ? v0 : v1, 4);
        t += __shfl_xor(t, 8);
        t += __shfl_xor(t, 16);
        t += __shfl_xor(t, 32);
        const float zec = t + biv;  // lane holds z_e[c = lane&7]
        float nn = zec * zec;
        nn += __shfl_xor(nn, 1);
        nn += __shfl_xor(nn, 2);
        nn += __shfl_xor(nn, 4);
        const float den = fmaxf(sqrtf(nn), EPSF);
        const float ec = zec / den;
        float e2 = ec * ec;
        e2 += __shfl_xor(e2, 1);
        e2 += __shfl_xor(e2, 2);
        e2 += __shfl_xor(e2, 4);
        e2v[cc] = e2;
#pragma unroll
        for (int c = 0; c < 8; ++c) ef[cc][c] = __shfl(ec, c);
      }

      // ---- dist + argmin: CA/CB global (L2, issued ~5k cy after DMAs ->
      // free drain; 16-deep ILP hides latency), NN from LDS ----------------
      const float* CA = cbnAg + (size_t)nq * Kn * 4;
      const float* CB = cbnBg + (size_t)nq * Kn * 4;
      float bdv[4];
      int bkv[4];
#pragma unroll
      for (int cc = 0; cc < 4; ++cc) { bdv[cc] = 1e30f; bkv[cc] = 0; }
#pragma unroll 4
      for (int mi = 0; mi < 16; ++mi) {
        const int k = (mi << 6) + lane;
        const float4 c0 = *(const float4*)(CA + (k << 2));
        const float4 c1 = *(const float4*)(CB + (k << 2));
        const float nnk = NN[k];
#pragma unroll
        for (int cc = 0; cc < 4; ++cc) {
          float dot = c0.x * ef[cc][0];
          dot = fmaf(c0.y, ef[cc][1], dot);
          dot = fmaf(c0.z, ef[cc][2], dot);
          dot = fmaf(c0.w, ef[cc][3], dot);
          dot = fmaf(c1.x, ef[cc][4], dot);
          dot = fmaf(c1.y, ef[cc][5], dot);
          dot = fmaf(c1.z, ef[cc][6], dot);
          dot = fmaf(c1.w, ef[cc][7], dot);
          const float dd = fmaf(-2.f, dot, e2v[cc]) + nnk;
          if (dd < bdv[cc]) { bdv[cc] = dd; bkv[cc] = k; }  // first-min in k
        }
      }
#pragma unroll
      for (int mask = 1; mask <= 32; mask <<= 1) {
#pragma unroll
        for (int cc = 0; cc < 4; ++cc) {
          const float od = __shfl_xor(bdv[cc], mask);
          const int ok = __shfl_xor(bkv[cc], mask);
          const bool take = (od < bdv[cc]) || (od == bdv[cc] && ok < bkv[cc]);
          bdv[cc] = take ? od : bdv[cc];
          bkv[cc] = take ? ok : bkv[cc];
        }
      }
      if (lane == 0) {
        float4 iv;
        iv.x = (float)bkv[0]; iv.y = (float)bkv[1];
        iv.z = (float)bkv[2]; iv.w = (float)bkv[3];
        *(float4*)(idxout + (size_t)(nq * Bn + b) * Tn + tcol) = iv;
      }

      // ---- gather raw codebook rows from global (uniform addr) -----------
      const float* CBR = cbraw + (size_t)nq * 8192;
      float zq[4][8];
#pragma unroll
      for (int cc = 0; cc < 4; ++cc) {
        const float4 q0 = *(const float4*)(CBR + (bkv[cc] << 3));
        const float4 q1 = *(const float4*)(CBR + (bkv[cc] << 3) + 4);
        zq[cc][0] = q0.x; zq[cc][1] = q0.y; zq[cc][2] = q0.z; zq[cc][3] = q0.w;
        zq[cc][4] = q1.x; zq[cc][5] = q1.y; zq[cc][6] = q1.z; zq[cc][7] = q1.w;
      }

      // ---- out_proj (global WT/BO, clean waits) + residual update --------
      const float* WT = wotg + (size_t)nq * 8192;
      const float* BO = b_out + (size_t)nq * 1024;
#pragma unroll
      for (int j = 0; j < 4; ++j) {
        const float4 bov = *(const float4*)(BO + (j << 8) + (lane << 2));
        float acc[4][4];
#pragma unroll
        for (int i = 0; i < 4; ++i)
#pragma unroll
          for (int cc = 0; cc < 4; ++cc) acc[i][cc] = 0.f;
#pragma unroll
        for (int c = 0; c < 8; ++c) {
          const float4 wv = *(const float4*)(WT + (c << 10) + (j << 8) + (lane << 2));
#pragma unroll
          for (int cc = 0; cc < 4; ++cc) {
            acc[0][cc] = fmaf(wv.x, zq[cc][c], acc[0][cc]);
            acc[1][cc] = fmaf(wv.y, zq[cc][c], acc[1][cc]);
            acc[2][cc] = fmaf(wv.z, zq[cc][c], acc[2][cc]);
            acc[3][cc] = fmaf(wv.w, zq[cc][c], acc[3][cc]);
          }
        }
#pragma unroll
        for (int i = 0; i < 4; ++i) {
          const float bod = (i == 0) ? bov.x : (i == 1) ? bov.y : (i == 2) ? bov.z : bov.w;
#pragma unroll
          for (int cc = 0; cc < 4; ++cc) {
            const float zo = acc[i][cc] + bod;
            r[cc][(j << 2) + i] = fmaf(-m[cc], zo, r[cc][(j << 2) + i]);
          }
        }
      }
    }  // active

    // ---- single wait+barrier per nq (block-local; blocks drift freely) ---
    asm volatile("s_waitcnt vmcnt(0)" ::: "memory");
    __syncthreads();
    cur ^= 1;
  }  // nq

  if (!active) return;

  // ---- final: qout = (z - residual) * mask --------------------------------
#pragma unroll
  for (int j = 0; j < 4; ++j) {
#pragma unroll
    for (int i = 0; i < 4; ++i) {
      const int d = (j << 8) + (lane << 2) + i;
      const float4 a0 = *(const float4*)(z + zb + (size_t)d * Tn + tcol);
      const int q = (j << 2) + i;
      float4 o0;
      o0.x = (a0.x - r[0][q]) * m[0];
      o0.y = (a0.y - r[1][q]) * m[1];
      o0.z = (a0.z - r[2][q]) * m[2];
      o0.w = (a0.w - r[3][q]) * m[3];
      *(float4*)(qout + zb + (size_t)d * Tn + tcol) = o0;
    }
  }
}

extern "C" void kernel_launch(void* const* d_in, const int* in_sizes, int n_in,
                              void* d_out, int out_size, void* d_ws, size_t ws_size,
                              hipStream_t stream) {
  const float* z = (const float*)d_in[0];
  const int* input_length = (const int*)d_in[1];
  const float* W_in = (const float*)d_in[2];
  const float* b_in = (const float*)d_in[3];
  const float* W_out = (const float*)d_in[4];
  const float* b_out = (const float*)d_in[5];
  const float* codebooks = (const float*)d_in[6];
  float* out = (float*)d_out;

  float* wsf = (float*)d_ws;
  float* cbnA = wsf;                          // 32*1024*4 floats
  float* cbnB = cbnA + (size_t)NQn * Kn * 4;  // 32*1024*4
  float* n2 = cbnB + (size_t)NQn * Kn * 4;    // 32*1024
  float* wot = n2 + (size_t)NQn * Kn;         // 32*8192
  int* midx = (int*)(wot + (size_t)NQn * CDn * Dn);

  prep_cbn_kernel<<<(NQn * Kn + 255) / 256, 256, 0, stream>>>(codebooks, cbnA, cbnB, n2);
  prep_wot_kernel<<<(NQn * Dn * CDn + 255) / 256, 256, 0, stream>>>(W_out, wot);
  prep_midx_kernel<<<NQn, 64, 0, stream>>>(b_in, cbnA, cbnB, n2, midx);
  fill_masked_kernel<<<8 * 64, 256, 0, stream>>>(input_length, midx, out);
  rvq_main_kernel<<<(Bn * Tn / 4) / 4, 256, 0, stream>>>(
      z, input_length, W_in, b_in, wot, b_out, codebooks, cbnA, cbnB, n2, out);
}

// Round 12
// 891.132 us; speedup vs baseline: 1.5044x; 1.1533x over previous
//
#include <hip/hip_runtime.h>
#include <math.h>

constexpr int Bn = 8, Dn = 1024, Tn = 4096, NQn = 32, Kn = 1024, CDn = 8;
constexpr float EPSF = 1e-12f;

// ---- exact shfl_xor replacements (same lane movement, cheaper pipes) ------
// DPP (VALU, no DS): xor1 = quad_perm[1,0,3,2]=0xB1; xor2 = quad_perm[2,3,0,1]
// =0x4E; xor8 = row_ror:8 = 0x128 ((i+8)%16 == i^8). bound_ctrl=1, full masks
// -> all lanes valid, movement identical to __shfl_xor.
template <int CTRL>
__device__ __forceinline__ int xdppi(int x) {
  return __builtin_amdgcn_update_dpp(0, x, CTRL, 0xF, 0xF, true);
}
template <int CTRL>
__device__ __forceinline__ float xdppf(float x) {
  return __int_as_float(xdppi<CTRL>(__float_as_int(x)));
}
// ds_swizzle BitMode: new_lane = ((lane & and) | or) ^ xor (within 32-half).
// xor4 = 0x101F, xor16 = 0x401F; bcast-of-channel-c = and 0x18 | (c<<5).
template <int PAT>
__device__ __forceinline__ int xswzi(int x) {
  return __builtin_amdgcn_ds_swizzle(x, PAT);
}
template <int PAT>
__device__ __forceinline__ float xswzf(float x) {
  return __int_as_float(xswzi<PAT>(__float_as_int(x)));
}

// ---- prepass 1: normalized codebooks as half-tables + squared norms -------
__global__ void prep_cbn_kernel(const float* __restrict__ cb,
                                float* __restrict__ cbnA,
                                float* __restrict__ cbnB,
                                float* __restrict__ n2) {
  const int idx = blockIdx.x * 256 + threadIdx.x;  // nq*K + k
  if (idx >= NQn * Kn) return;
  const float* row = cb + (size_t)idx * CDn;
  float v[8];
#pragma unroll
  for (int c = 0; c < 8; ++c) v[c] = row[c];
  float s = 0.f;
#pragma unroll
  for (int c = 0; c < 8; ++c) s += v[c] * v[c];
  const float den = fmaxf(sqrtf(s), EPSF);
  float nv[8];
#pragma unroll
  for (int c = 0; c < 8; ++c) nv[c] = v[c] / den;
  float s2 = 0.f;
#pragma unroll
  for (int c = 0; c < 8; ++c) s2 += nv[c] * nv[c];
#pragma unroll
  for (int c = 0; c < 4; ++c) cbnA[idx * 4 + c] = nv[c];
#pragma unroll
  for (int c = 0; c < 4; ++c) cbnB[idx * 4 + c] = nv[c + 4];
  n2[idx] = s2;
}

// ---- prepass 1b: transpose W_out [nq][d][c] -> [nq][c][d] -----------------
__global__ void prep_wot_kernel(const float* __restrict__ wo,
                                float* __restrict__ wot) {
  const int id = blockIdx.x * 256 + threadIdx.x;  // nq*8192 + d*8 + c
  if (id >= NQn * Dn * CDn) return;
  const int nq = id >> 13;
  const int rem = id & 8191;
  const int d = rem >> 3;
  const int c = rem & 7;
  wot[nq * 8192 + c * 1024 + d] = wo[id];
}

// ---- prepass 2: argmin index for fully-masked positions -------------------
__global__ void prep_midx_kernel(const float* __restrict__ b_in,
                                 const float* __restrict__ cbnA,
                                 const float* __restrict__ cbnB,
                                 const float* __restrict__ n2,
                                 int* __restrict__ midx) {
  const int nq = blockIdx.x;
  const int lane = threadIdx.x;  // 64 threads = 1 wave
  const float* bi = b_in + nq * CDn;
  float ze[8];
#pragma unroll
  for (int c = 0; c < 8; ++c) ze[c] = bi[c];
  float s = 0.f;
#pragma unroll
  for (int c = 0; c < 8; ++c) s += ze[c] * ze[c];
  const float den = fmaxf(sqrtf(s), EPSF);
  float enc[8];
#pragma unroll
  for (int c = 0; c < 8; ++c) enc[c] = ze[c] / den;
  float e2 = 0.f;
#pragma unroll
  for (int c = 0; c < 8; ++c) e2 += enc[c] * enc[c];

  const float* CA = cbnA + (size_t)nq * Kn * 4;
  const float* CB = cbnB + (size_t)nq * Kn * 4;
  const float* NN = n2 + (size_t)nq * Kn;
  float bd = 1e30f;
  int bk = 0;
#pragma unroll 4
  for (int mi = 0; mi < 16; ++mi) {
    const int k = (mi << 6) + lane;
    const float4 c0 = *(const float4*)(CA + (k << 2));
    const float4 c1 = *(const float4*)(CB + (k << 2));
    const float nnk = NN[k];
    float dot = c0.x * enc[0];
    dot = fmaf(c0.y, enc[1], dot);
    dot = fmaf(c0.z, enc[2], dot);
    dot = fmaf(c0.w, enc[3], dot);
    dot = fmaf(c1.x, enc[4], dot);
    dot = fmaf(c1.y, enc[5], dot);
    dot = fmaf(c1.z, enc[6], dot);
    dot = fmaf(c1.w, enc[7], dot);
    const float dd = fmaf(-2.f, dot, e2) + nnk;
    if (dd < bd) { bd = dd; bk = k; }
  }
#pragma unroll
  for (int mask = 1; mask <= 32; mask <<= 1) {
    const float od = __shfl_xor(bd, mask);
    const int ok = __shfl_xor(bk, mask);
    const bool take = (od < bd) || (od == bd && ok < bk);
    bd = take ? od : bd;
    bk = take ? ok : bk;
  }
  if (lane == 0) midx[nq] = bk;
}

// ---- masked-region fill: qout=0, idx=midx for t >= ceil(len/4)*4 ----------
__global__ void fill_masked_kernel(const int* __restrict__ lenp,
                                   const int* __restrict__ midx,
                                   float* __restrict__ out) {
  const int blk = blockIdx.x;  // 8 b x 64 chunks of 64 t
  const int b = blk >> 6;
  const int tstart = (blk & 63) << 6;
  const int tid = threadIdx.x;
  float* qout = out;
  float* idxout = out + (size_t)Bn * Dn * Tn;
  float* lenout = idxout + (size_t)NQn * Bn * Tn;
  const int len = lenp[b];
  if (blk == 0 && tid < 8) lenout[tid] = (float)lenp[tid];
  const int ag4 = ((len + 3) >> 2) << 2;  // first masked t (4-aligned)
  if (tstart + 63 < ag4) return;          // chunk fully active
  const size_t zb = (size_t)b * Dn * Tn;
  float4 zv; zv.x = 0.f; zv.y = 0.f; zv.z = 0.f; zv.w = 0.f;
  // qout zeros: 1024 d x 16 quads
#pragma unroll 4
  for (int it = 0; it < 64; ++it) {
    const int idx = (it << 8) + tid;
    const int d = idx >> 4;
    const int t = tstart + ((idx & 15) << 2);
    if (t >= ag4) *(float4*)(qout + zb + (size_t)d * Tn + t) = zv;
  }
  // idx fills: 32 nq x 16 quads
#pragma unroll
  for (int it = 0; it < 2; ++it) {
    const int idx = (it << 8) + tid;
    const int nq = idx >> 4;
    const int t = tstart + ((idx & 15) << 2);
    if (t >= ag4) {
      const float v = (float)midx[nq];
      float4 iv; iv.x = v; iv.y = v; iv.z = v; iv.w = v;
      *(float4*)(idxout + (size_t)(nq * Bn + b) * Tn + t) = iv;
    }
  }
}

// ---- async global->LDS DMA, 16 B per lane ---------------------------------
__device__ __forceinline__ void dma_lds16(const float* g, float* l) {
  __builtin_amdgcn_global_load_lds(
      (const __attribute__((address_space(1))) void*)g,
      (__attribute__((address_space(3))) void*)l, 16, 0, 0);
}

// ---------------- main kernel ---------------------------------------------
// Structure = R8 exactly (820 us, VALUBusy 62%, proven no-spill, poison-free
// staging, one vmcnt(0)+barrier per nq). R12 changes ONLY the cross-lane
// ops: the reduce/argmin butterflies used 144 ds_bpermute/wave/nq (~25-30 cy
// each, serial chains ~14 deep) -- the DS pipe carried ~106 KB/wave/nq at
// ~65% utilization and the chains co-produce the 38% stall. Replacements
// (identical lane movement -> bit-identical output):
//   xor1/xor2 -> DPP quad_perm (VALU, ~4cy, no DS)
//   xor8      -> DPP row_ror:8 (VALU)
//   xor4/16   -> ds_swizzle (DS but no index-VGPR)
//   bcast c   -> ds_swizzle and-mask (values 8-lane periodic)
//   xor32     -> __shfl_xor (unchanged)
// ~68 DS ops/wave/nq move to VALU; reduce-chain DS depth 14 -> ~4.
// Spill tripwire: WRITE_SIZE ~80 MB; VGPR <= 128.
__global__ __launch_bounds__(512, 2) void rvq_main_kernel(
    const float* __restrict__ z, const int* __restrict__ lenp,
    const float* __restrict__ W_in, const float* __restrict__ b_in,
    const float* __restrict__ wotg, const float* __restrict__ b_out,
    const float* __restrict__ cbraw, const float* __restrict__ cbnAg,
    const float* __restrict__ cbnBg, const float* __restrict__ n2g,
    float* __restrict__ out) {
  __shared__ __align__(16) float sWi[2][8192];  // 64 KB dbuf (in_proj W)
  __shared__ __align__(16) float sCA[2][4096];  // 32 KB dbuf (cbn lo-half)
  __shared__ __align__(16) float sCB[2][4096];  // 32 KB dbuf (cbn hi-half)
  __shared__ __align__(16) float sNN[2][1024];  //  8 KB dbuf (cbn |.|^2)
  __shared__ __align__(16) float sBI[256];      //  1 KB static (b_in)

  const int tid = threadIdx.x;
  const int lane = tid & 63;
  const int w = tid >> 6;

  // ---- active-group packing ----------------------------------------------
  int pre[9];
  pre[0] = 0;
#pragma unroll
  for (int bb = 0; bb < 8; ++bb) pre[bb + 1] = pre[bb] + ((lenp[bb] + 3) >> 2);
  const int total = pre[8];
  const int g = blockIdx.x * 8 + w;
  if (blockIdx.x * 8 >= total) return;  // whole block idle (before barriers)
  const bool active = (g < total);      // wave-uniform

  int b = 0, tg = 0, len = 0;
  if (active) {
    while (g >= pre[b + 1]) ++b;
    tg = g - pre[b];
    len = lenp[b];
  }
  const int tcol = tg << 2;
  const size_t zb = (size_t)b * Dn * Tn;

  float* qout = out;
  float* idxout = out + (size_t)Bn * Dn * Tn;

  float m[4];
#pragma unroll
  for (int cc = 0; cc < 4; ++cc) m[cc] = (tcol + cc < len) ? 1.0f : 0.0f;

  // ---- init residual = z * mask ------------------------------------------
  float r[4][16];
  if (active) {
#pragma unroll
    for (int j = 0; j < 4; ++j) {
#pragma unroll
      for (int i = 0; i < 4; ++i) {
        const int d = (j << 8) + (lane << 2) + i;
        const float4 a0 = *(const float4*)(z + zb + (size_t)d * Tn + tcol);
        const int q = (j << 2) + i;
        r[0][q] = a0.x * m[0]; r[1][q] = a0.y * m[1];
        r[2][q] = a0.z * m[2]; r[3][q] = a0.w * m[3];
      }
    }
  }

  const int b0 = lane & 1, b1 = (lane >> 1) & 1, b2 = (lane >> 2) & 1;

  // ---- prologue: stage Wi/CA/CB/NN(0) into buffer 0, b_in once -----------
  {
    const float* base = W_in + (w << 10);
    float* ldst = &sWi[0][w << 10];
#pragma unroll
    for (int q = 0; q < 4; ++q)
      dma_lds16(base + (q << 8) + (lane << 2), ldst + (q << 8));
    const float* baseA = cbnAg + (w << 9);
    const float* baseB = cbnBg + (w << 9);
    float* la = &sCA[0][w << 9];
    float* lb = &sCB[0][w << 9];
#pragma unroll
    for (int q = 0; q < 2; ++q)
      dma_lds16(baseA + (q << 8) + (lane << 2), la + (q << 8));
#pragma unroll
    for (int q = 0; q < 2; ++q)
      dma_lds16(baseB + (q << 8) + (lane << 2), lb + (q << 8));
    if (w == 0) {
#pragma unroll
      for (int q = 0; q < 4; ++q)
        dma_lds16(n2g + (q << 8) + (lane << 2), &sNN[0][q << 8]);
      dma_lds16(b_in + (lane << 2), sBI);
    }
  }
  asm volatile("s_waitcnt vmcnt(0)" ::: "memory");
  __syncthreads();

  int cur = 0;
#pragma unroll 1
  for (int nq = 0; nq < NQn; ++nq) {
    // ---- async prefetch Wi/CA/CB/NN(nq+1) into the other buffer ----------
    if (nq + 1 < NQn) {
      const float* base = W_in + (size_t)(nq + 1) * 8192 + (w << 10);
      float* ldst = &sWi[cur ^ 1][w << 10];
#pragma unroll
      for (int q = 0; q < 4; ++q)
        dma_lds16(base + (q << 8) + (lane << 2), ldst + (q << 8));
      const float* baseA = cbnAg + (size_t)(nq + 1) * 4096 + (w << 9);
      const float* baseB = cbnBg + (size_t)(nq + 1) * 4096 + (w << 9);
      float* la = &sCA[cur ^ 1][w << 9];
      float* lb = &sCB[cur ^ 1][w << 9];
#pragma unroll
      for (int q = 0; q < 2; ++q)
        dma_lds16(baseA + (q << 8) + (lane << 2), la + (q << 8));
#pragma unroll
      for (int q = 0; q < 2; ++q)
        dma_lds16(baseB + (q << 8) + (lane << 2), lb + (q << 8));
      if (w == 0) {
        const float* baseN = n2g + (size_t)(nq + 1) * 1024;
#pragma unroll
        for (int q = 0; q < 4; ++q)
          dma_lds16(baseN + (q << 8) + (lane << 2), &sNN[cur ^ 1][q << 8]);
      }
    }

    if (active) {
      const float* Wi = &sWi[cur][0];
      const float* CA = &sCA[cur][0];
      const float* CB = &sCB[cur][0];
      const float* NN = &sNN[cur][0];

      // ---- in_proj (LDS): per-lane partials over 16 d's, 8 channels ------
      float part[4][8];
#pragma unroll
      for (int cc = 0; cc < 4; ++cc)
#pragma unroll
        for (int c = 0; c < 8; ++c) part[cc][c] = 0.f;
#pragma unroll
      for (int c = 0; c < 8; ++c) {
#pragma unroll
        for (int j = 0; j < 4; ++j) {
          const float4 wv = *(const float4*)(Wi + (c << 10) + (j << 8) + (lane << 2));
#pragma unroll
          for (int cc = 0; cc < 4; ++cc) {
            part[cc][c] = fmaf(wv.x, r[cc][(j << 2) + 0], part[cc][c]);
            part[cc][c] = fmaf(wv.y, r[cc][(j << 2) + 1], part[cc][c]);
            part[cc][c] = fmaf(wv.z, r[cc][(j << 2) + 2], part[cc][c]);
            part[cc][c] = fmaf(wv.w, r[cc][(j << 2) + 3], part[cc][c]);
          }
        }
      }
      const float biv = sBI[(nq << 3) + (lane & 7)];

      // ---- transpose-reduce via DPP/swizzle butterfly (exact movement) ---
      float ef[4][8], e2v[4];
#pragma unroll
      for (int cc = 0; cc < 4; ++cc) {
        float u0, u1, u2, u3, v0, v1, t;
        {
          float k0 = b0 ? part[cc][1] : part[cc][0];
          float s0 = b0 ? part[cc][0] : part[cc][1];
          u0 = k0 + xdppf<0xB1>(s0);  // xor1
          float k1 = b0 ? part[cc][3] : part[cc][2];
          float s1 = b0 ? part[cc][2] : part[cc][3];
          u1 = k1 + xdppf<0xB1>(s1);
          float k2 = b0 ? part[cc][5] : part[cc][4];
          float s2 = b0 ? part[cc][4] : part[cc][5];
          u2 = k2 + xdppf<0xB1>(s2);
          float k3 = b0 ? part[cc][7] : part[cc][6];
          float s3 = b0 ? part[cc][6] : part[cc][7];
          u3 = k3 + xdppf<0xB1>(s3);
        }
        v0 = (b1 ? u1 : u0) + xdppf<0x4E>(b1 ? u0 : u1);      // xor2
        v1 = (b1 ? u3 : u2) + xdppf<0x4E>(b1 ? u2 : u3);
        t = (b2 ? v1 : v0) + xswzf<0x101F>(b2 ? v0 : v1);     // xor4
        t += xdppf<0x128>(t);                                 // xor8
        t += xswzf<0x401F>(t);                                // xor16
        t += __shfl_xor(t, 32);                               // xor32
        const float zec = t + biv;  // lane holds z_e[c = lane&7]
        float nn = zec * zec;
        nn += xdppf<0xB1>(nn);
        nn += xdppf<0x4E>(nn);
        nn += xswzf<0x101F>(nn);
        const float den = fmaxf(sqrtf(nn), EPSF);
        const float ec = zec / den;
        float e2 = ec * ec;
        e2 += xdppf<0xB1>(e2);
        e2 += xdppf<0x4E>(e2);
        e2 += xswzf<0x101F>(e2);
        e2v[cc] = e2;
        // bcast channel c to all lanes (values are 8-lane periodic)
        ef[cc][0] = xswzf<0x018>(ec);
        ef[cc][1] = xswzf<0x038>(ec);
        ef[cc][2] = xswzf<0x058>(ec);
        ef[cc][3] = xswzf<0x078>(ec);
        ef[cc][4] = xswzf<0x098>(ec);
        ef[cc][5] = xswzf<0x0B8>(ec);
        ef[cc][6] = xswzf<0x0D8>(ec);
        ef[cc][7] = xswzf<0x0F8>(ec);
      }

      // ---- dist + argmin over K=1024, all operands from LDS --------------
      float bdv[4];
      int bkv[4];
#pragma unroll
      for (int cc = 0; cc < 4; ++cc) { bdv[cc] = 1e30f; bkv[cc] = 0; }
#pragma unroll 4
      for (int mi = 0; mi < 16; ++mi) {
        const int k = (mi << 6) + lane;
        const float4 c0 = *(const float4*)(CA + (k << 2));
        const float4 c1 = *(const float4*)(CB + (k << 2));
        const float nnk = NN[k];
#pragma unroll
        for (int cc = 0; cc < 4; ++cc) {
          float dot = c0.x * ef[cc][0];
          dot = fmaf(c0.y, ef[cc][1], dot);
          dot = fmaf(c0.z, ef[cc][2], dot);
          dot = fmaf(c0.w, ef[cc][3], dot);
          dot = fmaf(c1.x, ef[cc][4], dot);
          dot = fmaf(c1.y, ef[cc][5], dot);
          dot = fmaf(c1.z, ef[cc][6], dot);
          dot = fmaf(c1.w, ef[cc][7], dot);
          const float dd = fmaf(-2.f, dot, e2v[cc]) + nnk;
          if (dd < bdv[cc]) { bdv[cc] = dd; bkv[cc] = k; }  // first-min in k
        }
      }
      // argmin butterfly, same movement as __shfl_xor masks 1..32
#pragma unroll
      for (int cc = 0; cc < 4; ++cc) {
        {
          const float od = xdppf<0xB1>(bdv[cc]);
          const int ok = xdppi<0xB1>(bkv[cc]);
          const bool take = (od < bdv[cc]) || (od == bdv[cc] && ok < bkv[cc]);
          bdv[cc] = take ? od : bdv[cc];
          bkv[cc] = take ? ok : bkv[cc];
        }
        {
          const float od = xdppf<0x4E>(bdv[cc]);
          const int ok = xdppi<0x4E>(bkv[cc]);
          const bool take = (od < bdv[cc]) || (od == bdv[cc] && ok < bkv[cc]);
          bdv[cc] = take ? od : bdv[cc];
          bkv[cc] = take ? ok : bkv[cc];
        }
        {
          const float od = xswzf<0x101F>(bdv[cc]);
          const int ok = xswzi<0x101F>(bkv[cc]);
          const bool take = (od < bdv[cc]) || (od == bdv[cc] && ok < bkv[cc]);
          bdv[cc] = take ? od : bdv[cc];
          bkv[cc] = take ? ok : bkv[cc];
        }
        {
          const float od = xdppf<0x128>(bdv[cc]);
          const int ok = xdppi<0x128>(bkv[cc]);
          const bool take = (od < bdv[cc]) || (od == bdv[cc] && ok < bkv[cc]);
          bdv[cc] = take ? od : bdv[cc];
          bkv[cc] = take ? ok : bkv[cc];
        }
        {
          const float od = xswzf<0x401F>(bdv[cc]);
          const int ok = xswzi<0x401F>(bkv[cc]);
          const bool take = (od < bdv[cc]) || (od == bdv[cc] && ok < bkv[cc]);
          bdv[cc] = take ? od : bdv[cc];
          bkv[cc] = take ? ok : bkv[cc];
        }
        {
          const float od = __shfl_xor(bdv[cc], 32);
          const int ok = __shfl_xor(bkv[cc], 32);
          const bool take = (od < bdv[cc]) || (od == bdv[cc] && ok < bkv[cc]);
          bdv[cc] = take ? od : bdv[cc];
          bkv[cc] = take ? ok : bkv[cc];
        }
      }

      // ---- gather raw codebook rows (FIRST ordinary global loads of this
      // iteration -- their wait drains the long-finished prefetch for free).
      const float* CBR = cbraw + (size_t)nq * 8192;
      float zq[4][8];
#pragma unroll
      for (int cc = 0; cc < 4; ++cc) {
        const float4 q0 = *(const float4*)(CBR + (bkv[cc] << 3));
        const float4 q1 = *(const float4*)(CBR + (bkv[cc] << 3) + 4);
        zq[cc][0] = q0.x; zq[cc][1] = q0.y; zq[cc][2] = q0.z; zq[cc][3] = q0.w;
        zq[cc][4] = q1.x; zq[cc][5] = q1.y; zq[cc][6] = q1.z; zq[cc][7] = q1.w;
      }
      if (lane == 0) {
        float4 iv;
        iv.x = (float)bkv[0]; iv.y = (float)bkv[1];
        iv.z = (float)bkv[2]; iv.w = (float)bkv[3];
        *(float4*)(idxout + (size_t)(nq * Bn + b) * Tn + tcol) = iv;
      }

      // ---- out_proj (global WT/BO, clean waits) + residual update --------
      const float* WT = wotg + (size_t)nq * 8192;
      const float* BO = b_out + (size_t)nq * 1024;
#pragma unroll
      for (int j = 0; j < 4; ++j) {
        const float4 bov = *(const float4*)(BO + (j << 8) + (lane << 2));
        float acc[4][4];
#pragma unroll
        for (int i = 0; i < 4; ++i)
#pragma unroll
          for (int cc = 0; cc < 4; ++cc) acc[i][cc] = 0.f;
#pragma unroll
        for (int c = 0; c < 8; ++c) {
          const float4 wv = *(const float4*)(WT + (c << 10) + (j << 8) + (lane << 2));
#pragma unroll
          for (int cc = 0; cc < 4; ++cc) {
            acc[0][cc] = fmaf(wv.x, zq[cc][c], acc[0][cc]);
            acc[1][cc] = fmaf(wv.y, zq[cc][c], acc[1][cc]);
            acc[2][cc] = fmaf(wv.z, zq[cc][c], acc[2][cc]);
            acc[3][cc] = fmaf(wv.w, zq[cc][c], acc[3][cc]);
          }
        }
#pragma unroll
        for (int i = 0; i < 4; ++i) {
          const float bod = (i == 0) ? bov.x : (i == 1) ? bov.y : (i == 2) ? bov.z : bov.w;
#pragma unroll
          for (int cc = 0; cc < 4; ++cc) {
            const float zo = acc[i][cc] + bod;
            r[cc][(j << 2) + i] = fmaf(-m[cc], zo, r[cc][(j << 2) + i]);
          }
        }
      }
    }  // active

    // ---- single wait+barrier per nq: prefetch DMAs drained (all waves,
    // already complete), LDS reads retired -> buffers swap safely. ---------
    asm volatile("s_waitcnt vmcnt(0)" ::: "memory");
    __syncthreads();
    cur ^= 1;
  }  // nq

  if (!active) return;

  // ---- final: qout = (z - residual) * mask --------------------------------
#pragma unroll
  for (int j = 0; j < 4; ++j) {
#pragma unroll
    for (int i = 0; i < 4; ++i) {
      const int d = (j << 8) + (lane << 2) + i;
      const float4 a0 = *(const float4*)(z + zb + (size_t)d * Tn + tcol);
      const int q = (j << 2) + i;
      float4 o0;
      o0.x = (a0.x - r[0][q]) * m[0];
      o0.y = (a0.y - r[1][q]) * m[1];
      o0.z = (a0.z - r[2][q]) * m[2];
      o0.w = (a0.w - r[3][q]) * m[3];
      *(float4*)(qout + zb + (size_t)d * Tn + tcol) = o0;
    }
  }
}

extern "C" void kernel_launch(void* const* d_in, const int* in_sizes, int n_in,
                              void* d_out, int out_size, void* d_ws, size_t ws_size,
                              hipStream_t stream) {
  const float* z = (const float*)d_in[0];
  const int* input_length = (const int*)d_in[1];
  const float* W_in = (const float*)d_in[2];
  const float* b_in = (const float*)d_in[3];
  const float* W_out = (const float*)d_in[4];
  const float* b_out = (const float*)d_in[5];
  const float* codebooks = (const float*)d_in[6];
  float* out = (float*)d_out;

  float* wsf = (float*)d_ws;
  float* cbnA = wsf;                          // 32*1024*4 floats
  float* cbnB = cbnA + (size_t)NQn * Kn * 4;  // 32*1024*4
  float* n2 = cbnB + (size_t)NQn * Kn * 4;    // 32*1024
  float* wot = n2 + (size_t)NQn * Kn;         // 32*8192
  int* midx = (int*)(wot + (size_t)NQn * CDn * Dn);

  prep_cbn_kernel<<<(NQn * Kn + 255) / 256, 256, 0, stream>>>(codebooks, cbnA, cbnB, n2);
  prep_wot_kernel<<<(NQn * Dn * CDn + 255) / 256, 256, 0, stream>>>(W_out, wot);
  prep_midx_kernel<<<NQn, 64, 0, stream>>>(b_in, cbnA, cbnB, n2, midx);
  fill_masked_kernel<<<8 * 64, 256, 0, stream>>>(input_length, midx, out);
  rvq_main_kernel<<<(Bn * Tn / 4) / 8, 512, 0, stream>>>(
      z, input_length, W_in, b_in, wot, b_out, codebooks, cbnA, cbnB, n2, out);
}